// Round 4
// baseline (212.218 us; speedup 1.0000x reference)
//
#include <hip/hip_runtime.h>
#include <hip/hip_bf16.h>

#define N_NODES 8192
#define N_IN 512
#define N_OUT 512

typedef __bf16 bf16;
typedef __bf16 bf16x4 __attribute__((ext_vector_type(4)));
typedef __bf16 bf16x8 __attribute__((ext_vector_type(8)));
typedef float f32x4 __attribute__((ext_vector_type(4)));

__device__ __forceinline__ void gload16(const void* g, void* l) {
  __builtin_amdgcn_global_load_lds((const __attribute__((address_space(1))) void*)g,
                                   (__attribute__((address_space(3))) void*)l, 16, 0, 0);
}

#define WAITVM(N) asm volatile("s_waitcnt vmcnt(" #N ")" ::: "memory")
#define BAR() do { asm volatile("" ::: "memory"); __builtin_amdgcn_s_barrier(); \
                   asm volatile("" ::: "memory"); } while (0)

// ---- kernel 1: column partial sums + fp32->bf16 convert, +I folded into diagonal ----
__global__ __launch_bounds__(256) void k_colsum_cvt(const float* __restrict__ adj,
                                                    bf16* __restrict__ adjb,
                                                    float* __restrict__ partial) {
  const int tid  = threadIdx.x;
  const int col0 = blockIdx.x * 1024 + tid * 4;
  const int row0 = blockIdx.y * 64;
  float s0 = 0.f, s1 = 0.f, s2 = 0.f, s3 = 0.f;
#pragma unroll 4
  for (int r = 0; r < 64; ++r) {
    float4 v = *reinterpret_cast<const float4*>(adj + (size_t)(row0 + r) * N_NODES + col0);
    s0 += v.x; s1 += v.y; s2 += v.z; s3 += v.w;   // degree uses ORIGINAL adj (+1 via init)
    const int dq = row0 + r - col0;               // fold identity: adjb[i][i] = adj[i][i]+1
    if ((unsigned)dq < 4u) reinterpret_cast<float*>(&v)[dq] += 1.0f;
    bf16x4 o = { (bf16)v.x, (bf16)v.y, (bf16)v.z, (bf16)v.w };
    *reinterpret_cast<bf16x4*>(adjb + (size_t)(row0 + r) * N_NODES + col0) = o;
  }
  float4 ps = { s0, s1, s2, s3 };
  *reinterpret_cast<float4*>(partial + (size_t)blockIdx.y * N_NODES + col0) = ps;
}

// ---- kernel 2: d[j] = rsqrt(1 + colsum) ----
__global__ __launch_bounds__(256) void k_dvec(const float* __restrict__ partial,
                                              float* __restrict__ dv) {
  const int j = blockIdx.x * 256 + threadIdx.x;
  float s = 1.0f;  // +1 from the identity (self-loop)
#pragma unroll 8
  for (int p = 0; p < 128; ++p) s += partial[(size_t)p * N_NODES + j];
  dv[j] = rsqrtf(s);
}

// ---- kernel 3: Hst[k][j] = d[j]*H[j][k]  (transpose+scale, bf16; B^T layout for GEMM1) ----
__global__ __launch_bounds__(256) void k_hst(const float* __restrict__ H,
                                             const float* __restrict__ dv,
                                             bf16* __restrict__ Hst) {
  __shared__ float t[64][65];
  const int tid = threadIdx.x;
  const int j0 = blockIdx.x * 64;
  const int k0 = blockIdx.y * 64;
  const int rr = tid >> 4;         // 0..15
  const int cc = (tid & 15) * 4;   // 0..60
#pragma unroll
  for (int p = 0; p < 4; ++p) {
    const int r = p * 16 + rr;
    const float d = dv[j0 + r];
    float4 v = *reinterpret_cast<const float4*>(H + (size_t)(j0 + r) * N_IN + k0 + cc);
    t[r][cc + 0] = v.x * d; t[r][cc + 1] = v.y * d;
    t[r][cc + 2] = v.z * d; t[r][cc + 3] = v.w * d;
  }
  __syncthreads();
#pragma unroll
  for (int p = 0; p < 4; ++p) {
    const int kr = p * 16 + rr;
    bf16x4 o = { (bf16)t[cc + 0][kr], (bf16)t[cc + 1][kr],
                 (bf16)t[cc + 2][kr], (bf16)t[cc + 3][kr] };
    *reinterpret_cast<bf16x4*>(Hst + (size_t)(k0 + kr) * N_NODES + j0 + cc) = o;
  }
}

// ---- kernel 4: W fp32 -> bf16 (already B^T layout: [NOUT][NIN]) ----
__global__ __launch_bounds__(256) void k_wcvt(const float* __restrict__ W, bf16* __restrict__ Wb) {
  const int i = (blockIdx.x * 256 + threadIdx.x) * 4;
  float4 v = *reinterpret_cast<const float4*>(W + i);
  bf16x4 o = { (bf16)v.x, (bf16)v.y, (bf16)v.z, (bf16)v.w };
  *reinterpret_cast<bf16x4*>(Wb + i) = o;
}

// ================= 256x256-tile GEMM (gemm1): P[split] = A @ B^T ==================
// Phase-split schedule (T3+T4+T5): BK=32, 4 LDS buffers, 2 phases per K-tile of
// 16 MFMA each; each phase issues 2 global_load_lds for tile t+2 into the dead
// buffer; counted vmcnt(4) ONCE per K-tile (0 only at drain); setprio around
// each MFMA cluster; both-sides XOR swizzle (2-way max aliasing = free).
template<int KDIM, int NSPLIT>
__global__ __launch_bounds__(512, 2) void k_gemm256(
    const bf16* __restrict__ A, const bf16* __restrict__ B, float* __restrict__ P) {
  constexpr int KSEG = KDIM / NSPLIT;
  constexpr int NT = KSEG / 32;                // 64 K-tiles
  constexpr int NTN = 2;                       // N=512 -> 2 N-tiles of 256
  constexpr int NBLK = 32 * NTN * NSPLIT;
  __shared__ __attribute__((aligned(128))) char lds[4 * 32768];

  // XCD swizzle (NBLK%8==0 -> bijective); N-minor for A-panel L2 reuse.
  const int bid = blockIdx.x;
  const int logical = (bid & 7) * (NBLK / 8) + (bid >> 3);
  const int split = logical / (32 * NTN);
  const int rem = logical % (32 * NTN);
  const int bm0 = (rem >> 1) * 256;
  const int bn0 = (rem & 1) * 256;

  const int tid = threadIdx.x;
  const int lane = tid & 63;
  const int wid = tid >> 6;
  const int wr = wid >> 2;                     // 0..1  (M half, 128 rows)
  const int wc = wid & 3;                      // 0..3  (N quarter, 64 cols)

  // staging: linear LDS dest (global_load_lds), INVERSE-swizzled global source
  const int srow = tid >> 2;                   // 0..127
  const int scol = ((tid & 3) ^ ((srow >> 1) & 3)) << 3;   // elements
  const size_t a_src = (size_t)(bm0 + srow) * KDIM + (size_t)split * KSEG + scol;
  const size_t b_src = (size_t)(bn0 + srow) * KDIM + (size_t)split * KSEG + scol;

  // fragment reads (swizzled): byte = row*64 + (fk*16 ^ ((row>>1)&3)*16)
  const int frow = lane & 15;
  const int fk = lane >> 4;                    // 0..3
  const int colb = (fk << 4) ^ (((frow >> 1) & 3) << 4);
  const int a_base = (wr * 128 + frow) * 64 + colb;
  const int b_base = 16384 + (wc * 64 + frow) * 64 + colb;

  f32x4 acc[8][4] = {};

  auto stage_full = [&](int t) {               // prologue only: all 4 chunks
    char* sb = lds + (t & 3) * 32768;
    const bf16* ag = A + a_src + (size_t)t * 32;
    const bf16* bg = B + b_src + (size_t)t * 32;
    gload16(ag,                      sb +         tid * 16);
    gload16(ag + (size_t)128 * KDIM, sb +  8192 + tid * 16);
    gload16(bg,                      sb + 16384 + tid * 16);
    gload16(bg + (size_t)128 * KDIM, sb + 24576 + tid * 16);
  };

  stage_full(0); stage_full(1);
  WAITVM(4);                                   // tile 0 landed; tile 1 in flight
  BAR();

#pragma unroll 1
  for (int t = 0; t < NT; ++t) {
    const char* lbase = lds + (t & 3) * 32768;
    char* sbase = lds + ((t + 2) & 3) * 32768; // dead buffer (tile t-2 consumed)
    const bf16* ag = A + a_src + (size_t)(t + 2) * 32;
    const bf16* bg = B + b_src + (size_t)(t + 2) * 32;
    const bool pf = (t + 2 < NT);

    bf16x8 av[8], bv[4];
    // ---------------- phase A: frags m0-3 + all B, stage A-chunks ----------------
#pragma unroll
    for (int m = 0; m < 4; ++m)
      av[m] = *reinterpret_cast<const bf16x8*>(lbase + a_base + m * 1024);
#pragma unroll
    for (int n = 0; n < 4; ++n)
      bv[n] = *reinterpret_cast<const bf16x8*>(lbase + b_base + n * 1024);
    if (pf) {
      gload16(ag,                      sbase +        tid * 16);
      gload16(ag + (size_t)128 * KDIM, sbase + 8192 + tid * 16);
    }
    BAR();
    __builtin_amdgcn_s_setprio(1);
#pragma unroll
    for (int m = 0; m < 4; ++m)
#pragma unroll
      for (int n = 0; n < 4; ++n)
        acc[m][n] = __builtin_amdgcn_mfma_f32_16x16x32_bf16(av[m], bv[n], acc[m][n], 0, 0, 0);
    __builtin_amdgcn_s_setprio(0);
    BAR();
    // ---------------- phase B: frags m4-7, stage B-chunks, K-tile fence ----------
#pragma unroll
    for (int m = 4; m < 8; ++m)
      av[m] = *reinterpret_cast<const bf16x8*>(lbase + a_base + m * 1024);
    if (pf) {
      gload16(bg,                      sbase + 16384 + tid * 16);
      gload16(bg + (size_t)128 * KDIM, sbase + 24576 + tid * 16);
    }
    BAR();
    __builtin_amdgcn_s_setprio(1);
#pragma unroll
    for (int m = 4; m < 8; ++m)
#pragma unroll
      for (int n = 0; n < 4; ++n)
        acc[m][n] = __builtin_amdgcn_mfma_f32_16x16x32_bf16(av[m], bv[n], acc[m][n], 0, 0, 0);
    __builtin_amdgcn_s_setprio(0);
    if (pf) WAITVM(4); else WAITVM(0);         // retire tile t+1's 4 loads (oldest)
    BAR();
  }

  // epilogue: C/D layout col = lane&15, row = (lane>>4)*4 + j
#pragma unroll
  for (int m = 0; m < 8; ++m) {
#pragma unroll
    for (int j = 0; j < 4; ++j) {
      const int grow = bm0 + wr * 128 + m * 16 + (lane >> 4) * 4 + j;
      float* prow = P + (size_t)split * ((size_t)N_NODES * N_IN) + (size_t)grow * N_IN;
#pragma unroll
      for (int n = 0; n < 4; ++n) {
        const int gcol = bn0 + wc * 64 + n * 16 + (lane & 15);
        prow[gcol] = acc[m][n][j];
      }
    }
  }
}

// ---- 128x128-tile GEMM (gemm2): out = tanh(A @ B^T + bias), verified structure ----
template<int KDIM>
__global__ __launch_bounds__(256, 2) void k_gemm(
    const bf16* __restrict__ A, const bf16* __restrict__ B,
    const float* __restrict__ bias, float* __restrict__ outf) {
  constexpr int NT = KDIM / 64;
  constexpr int NBLK = 256;
  __shared__ __attribute__((aligned(128))) char lds[2 * 32768];

  const int bid = blockIdx.x;
  const int logical = (bid & 7) * (NBLK / 8) + (bid >> 3);
  const int bm0 = (logical >> 2) * 128;
  const int bn0 = (logical & 3) * 128;

  const int tid = threadIdx.x;
  const int wid = tid >> 6;
  const int lane = tid & 63;
  const int wr = wid & 1, wc = wid >> 1;

  const int srow = tid >> 3;
  const int scol = ((tid & 7) ^ (srow & 7)) << 3;
  const size_t a_src = (size_t)(bm0 + srow) * KDIM + scol;
  const size_t b_src = (size_t)(bn0 + srow) * KDIM + scol;

  const int frow = lane & 15;
  const int fk = lane >> 4;
  const int swz = (lane & 7) << 4;
  const int a_row_byte = (wr * 64 + frow) * 128;
  const int b_row_byte = 16384 + (wc * 64 + frow) * 128;

  f32x4 acc[4][4] = {};

  auto stage = [&](int t) {
    char* lbase = lds + (t & 1) * 32768;
    const bf16* ag = A + a_src + (size_t)t * 64;
    const bf16* bg = B + b_src + (size_t)t * 64;
#pragma unroll
    for (int ch = 0; ch < 4; ++ch) {
      gload16(ag + (size_t)(ch * 32) * KDIM, lbase + ch * 4096 + wid * 1024);
      gload16(bg + (size_t)(ch * 32) * KDIM, lbase + 16384 + ch * 4096 + wid * 1024);
    }
  };

  auto compute = [&](int t) {
    const char* lbase = lds + (t & 1) * 32768;
#pragma unroll
    for (int kk = 0; kk < 2; ++kk) {
      const int colb = (kk * 64 + fk * 16) ^ swz;
      bf16x8 av[4], bv[4];
#pragma unroll
      for (int m = 0; m < 4; ++m)
        av[m] = *reinterpret_cast<const bf16x8*>(lbase + a_row_byte + m * 2048 + colb);
#pragma unroll
      for (int n = 0; n < 4; ++n)
        bv[n] = *reinterpret_cast<const bf16x8*>(lbase + b_row_byte + n * 2048 + colb);
#pragma unroll
      for (int m = 0; m < 4; ++m)
#pragma unroll
        for (int n = 0; n < 4; ++n)
          acc[m][n] = __builtin_amdgcn_mfma_f32_16x16x32_bf16(av[m], bv[n], acc[m][n], 0, 0, 0);
    }
  };

  stage(0);
#pragma unroll 1
  for (int t = 0; t < NT - 1; ++t) {
    stage(t + 1);
    WAITVM(8);
    BAR();
    compute(t);
    BAR();
  }
  WAITVM(0);
  BAR();
  compute(NT - 1);

#pragma unroll
  for (int m = 0; m < 4; ++m) {
#pragma unroll
    for (int j = 0; j < 4; ++j) {
      const int grow = bm0 + wr * 64 + m * 16 + (lane >> 4) * 4 + j;
      float* orow = outf + (size_t)grow * N_OUT;
#pragma unroll
      for (int n = 0; n < 4; ++n) {
        const int gcol = bn0 + wc * 64 + n * 16 + (lane & 15);
        float v = acc[m][n][j] + bias[gcol];
        v = fminf(fmaxf(v, -15.f), 15.f);
        const float e = __expf(2.f * v);
        orow[gcol] = (e - 1.f) / (e + 1.f);
      }
    }
  }
}

// ---- split-K reduce: Hm = bf16(d_i * (P0+P1+P2+P3))  (+I already inside adjb) ----
__global__ __launch_bounds__(256) void k_red(const float* __restrict__ P,
                                             const float* __restrict__ dv,
                                             bf16* __restrict__ Hm) {
  const int t = blockIdx.x * 256 + threadIdx.x;
  const int row = t >> 7;
  const int col = (t & 127) << 2;
  const size_t off = (size_t)row * N_IN + col;
  constexpr size_t S = (size_t)N_NODES * N_IN;
  const float d = dv[row];
  const float4 p0 = *reinterpret_cast<const float4*>(P + off);
  const float4 p1 = *reinterpret_cast<const float4*>(P + S + off);
  const float4 p2 = *reinterpret_cast<const float4*>(P + 2 * S + off);
  const float4 p3 = *reinterpret_cast<const float4*>(P + 3 * S + off);
  bf16x4 o = { (bf16)(d * ((p0.x + p1.x) + (p2.x + p3.x))),
               (bf16)(d * ((p0.y + p1.y) + (p2.y + p3.y))),
               (bf16)(d * ((p0.z + p1.z) + (p2.z + p3.z))),
               (bf16)(d * ((p0.w + p1.w) + (p2.w + p3.w))) };
  *reinterpret_cast<bf16x4*>(Hm + off) = o;
}

extern "C" void kernel_launch(void* const* d_in, const int* in_sizes, int n_in,
                              void* d_out, int out_size, void* d_ws, size_t ws_size,
                              hipStream_t stream) {
  const float* H   = (const float*)d_in[0];
  const float* adj = (const float*)d_in[1];
  const float* W   = (const float*)d_in[2];
  const float* b   = (const float*)d_in[3];
  float* out = (float*)d_out;
  char* ws = (char*)d_ws;

  bf16*  adjb = (bf16*)(ws);                    // 8192*8192*2 = 134217728
  bf16*  Hst  = (bf16*)(ws + 134217728);        // 512*8192*2  = 8388608
  bf16*  Hm   = (bf16*)(ws + 142606336);        // 8192*512*2  = 8388608
  bf16*  Wb   = (bf16*)(ws + 150994944);        // 512*512*2   = 524288
  float* part = (float*)(ws + 151519232);       // 128*8192*4  = 4194304
  float* dv   = (float*)(ws + 155713536);       // 8192*4      = 32768
  float* P    = (float*)(ws + 155746304);       // 4*8192*512*4 = 67108864

  k_colsum_cvt<<<dim3(8, 128), 256, 0, stream>>>(adj, adjb, part);
  k_dvec<<<32, 256, 0, stream>>>(part, dv);
  k_hst<<<dim3(128, 8), 256, 0, stream>>>(H, dv, Hst);
  k_wcvt<<<256, 256, 0, stream>>>(W, Wb);
  // P[s] = (adj+I)b[:, s-quarter] @ Hst[s-quarter]^T   (split-K=4, f32 partials)
  k_gemm256<8192, 4><<<256, 512, 0, stream>>>(adjb, Hst, P);
  // Hm = d_i*(P0+P1+P2+P3)   (bf16)
  k_red<<<4096, 256, 0, stream>>>(P, dv, Hm);
  // out = tanh(Hm @ W^T + b)  (f32)
  k_gemm<512><<<256, 256, 0, stream>>>(Hm, Wb, b, out);
}

// Round 5
// 206.622 us; speedup vs baseline: 1.0271x; 1.0271x over previous
//
#include <hip/hip_runtime.h>
#include <hip/hip_bf16.h>

#define N_NODES 8192
#define N_IN 512
#define N_OUT 512

typedef __bf16 bf16;
typedef __bf16 bf16x4 __attribute__((ext_vector_type(4)));
typedef __bf16 bf16x8 __attribute__((ext_vector_type(8)));
typedef float f32x4 __attribute__((ext_vector_type(4)));

__device__ __forceinline__ void gload16(const void* g, void* l) {
  __builtin_amdgcn_global_load_lds((const __attribute__((address_space(1))) void*)g,
                                   (__attribute__((address_space(3))) void*)l, 16, 0, 0);
}

#define WAITVM(N) asm volatile("s_waitcnt vmcnt(" #N ")" ::: "memory")
#define BAR() do { asm volatile("" ::: "memory"); __builtin_amdgcn_s_barrier(); \
                   asm volatile("" ::: "memory"); } while (0)

// ---- kernel 1: column partial sums + fp32->bf16 convert, +I folded into diagonal ----
__global__ __launch_bounds__(256) void k_colsum_cvt(const float* __restrict__ adj,
                                                    bf16* __restrict__ adjb,
                                                    float* __restrict__ partial) {
  const int tid  = threadIdx.x;
  const int col0 = blockIdx.x * 1024 + tid * 4;
  const int row0 = blockIdx.y * 64;
  float s0 = 0.f, s1 = 0.f, s2 = 0.f, s3 = 0.f;
#pragma unroll 4
  for (int r = 0; r < 64; ++r) {
    float4 v = *reinterpret_cast<const float4*>(adj + (size_t)(row0 + r) * N_NODES + col0);
    s0 += v.x; s1 += v.y; s2 += v.z; s3 += v.w;   // degree uses ORIGINAL adj (+1 via init)
    const int dq = row0 + r - col0;               // fold identity: adjb[i][i] = adj[i][i]+1
    if ((unsigned)dq < 4u) reinterpret_cast<float*>(&v)[dq] += 1.0f;
    bf16x4 o = { (bf16)v.x, (bf16)v.y, (bf16)v.z, (bf16)v.w };
    *reinterpret_cast<bf16x4*>(adjb + (size_t)(row0 + r) * N_NODES + col0) = o;
  }
  float4 ps = { s0, s1, s2, s3 };
  *reinterpret_cast<float4*>(partial + (size_t)blockIdx.y * N_NODES + col0) = ps;
}

// ---- kernel 2: d[j] = rsqrt(1 + colsum) ----
__global__ __launch_bounds__(256) void k_dvec(const float* __restrict__ partial,
                                              float* __restrict__ dv) {
  const int j = blockIdx.x * 256 + threadIdx.x;
  float s = 1.0f;  // +1 from the identity (self-loop)
#pragma unroll 8
  for (int p = 0; p < 128; ++p) s += partial[(size_t)p * N_NODES + j];
  dv[j] = rsqrtf(s);
}

// ---- kernel 3: Hst[k][j] = d[j]*H[j][k]  (transpose+scale, bf16; B^T layout for GEMM1) ----
__global__ __launch_bounds__(256) void k_hst(const float* __restrict__ H,
                                             const float* __restrict__ dv,
                                             bf16* __restrict__ Hst) {
  __shared__ float t[64][65];
  const int tid = threadIdx.x;
  const int j0 = blockIdx.x * 64;
  const int k0 = blockIdx.y * 64;
  const int rr = tid >> 4;         // 0..15
  const int cc = (tid & 15) * 4;   // 0..60
#pragma unroll
  for (int p = 0; p < 4; ++p) {
    const int r = p * 16 + rr;
    const float d = dv[j0 + r];
    float4 v = *reinterpret_cast<const float4*>(H + (size_t)(j0 + r) * N_IN + k0 + cc);
    t[r][cc + 0] = v.x * d; t[r][cc + 1] = v.y * d;
    t[r][cc + 2] = v.z * d; t[r][cc + 3] = v.w * d;
  }
  __syncthreads();
#pragma unroll
  for (int p = 0; p < 4; ++p) {
    const int kr = p * 16 + rr;
    bf16x4 o = { (bf16)t[cc + 0][kr], (bf16)t[cc + 1][kr],
                 (bf16)t[cc + 2][kr], (bf16)t[cc + 3][kr] };
    *reinterpret_cast<bf16x4*>(Hst + (size_t)(k0 + kr) * N_NODES + j0 + cc) = o;
  }
}

// ---- kernel 4: W fp32 -> bf16 (already B^T layout: [NOUT][NIN]) ----
__global__ __launch_bounds__(256) void k_wcvt(const float* __restrict__ W, bf16* __restrict__ Wb) {
  const int i = (blockIdx.x * 256 + threadIdx.x) * 4;
  float4 v = *reinterpret_cast<const float4*>(W + i);
  bf16x4 o = { (bf16)v.x, (bf16)v.y, (bf16)v.z, (bf16)v.w };
  *reinterpret_cast<bf16x4*>(Wb + i) = o;
}

// ============== 256x256-tile GEMM (gemm1), m201-class schedule ==============
// BK=64 (128B LDS rows -> 8 slots, XOR row&7 swizzle = conflict-free class),
// 2 x 64KB LDS double-buffer, 8 waves (2Mx4N, wave-tile 128x64), 4 phases per
// K-tile of 16 MFMA each, per-phase quarter-tile staging via global_load_lds,
// counted vmcnt (10/8 steady; 8/2/0 tail only), setprio around MFMA clusters.
//
// Per-iter gload ledger (per wave; 1 quarter = 1 gload):
//   ph1: A1,A3(kt+1)->other buf [2]   ph2: B0,B1(kt+2)->cur buf [2]
//   ph3: B2,B3,A0,A2(kt+2)->cur [4]   ph4: none
// Legality: B(kt) last read ph1; AQ0/AQ2(kt) last read ph2; AQ1/AQ3(kt) last
// read ph4 (staged next iter ph1). Fences: end-ph2 waits A1A3(kt) -> vmcnt(10);
// end-ph4 waits B+A0A2(kt+1) -> vmcnt(8).
template<int KDIM, int NSPLIT>
__global__ __launch_bounds__(512, 2) void k_gemm256(
    const bf16* __restrict__ A, const bf16* __restrict__ B, float* __restrict__ P) {
  constexpr int KSEG = KDIM / NSPLIT;
  constexpr int NT = KSEG / 64;                // 32 K-tiles
  constexpr int NTN = 2;                       // N=512 -> 2 N-tiles of 256
  constexpr int NBLK = 32 * NTN * NSPLIT;
  __shared__ __attribute__((aligned(128))) char lds[2 * 65536];

  // XCD swizzle (NBLK%8==0 -> bijective); N-minor for A-panel L2 reuse.
  const int bid = blockIdx.x;
  const int logical = (bid & 7) * (NBLK / 8) + (bid >> 3);
  const int split = logical / (32 * NTN);
  const int rem = logical % (32 * NTN);
  const int bm0 = (rem >> 1) * 256;
  const int bn0 = (rem & 1) * 256;

  const int tid = threadIdx.x;
  const int lane = tid & 63;
  const int wid = tid >> 6;
  const int wr = wid >> 2;                     // 0..1 (M half, 128 rows)
  const int wc = wid & 3;                      // 0..3 (N quarter, 64 cols)

  // staging: LDS dest = wave-uniform base (+ lane*16 in HW); global source is
  // per-lane, INVERSE-swizzled so phys slot s at row r holds logical s^(r&7).
  const int lrow = lane >> 3;                  // 0..7  (row&7 within quarter)
  const int g_srow = wid * 8 + lrow;           // 0..63 row within 64-row quarter
  const int g_scol = ((lane & 7) ^ lrow) << 3; // element col within K-tile
  const size_t koff = (size_t)split * KSEG;
  const bf16* aP = A + (size_t)(bm0 + g_srow) * KDIM + koff + g_scol;
  const bf16* bP = B + (size_t)(bn0 + g_srow) * KDIM + koff + g_scol;
  const int ldst = wid * 1024;

  // fragment reads: byte = row*128 + ((kk*4+fk) ^ (row&7))*16, row&7 == lane&7
  const int frow = lane & 15;
  const int fk = lane >> 4;                    // 0..3
  const int e7 = lane & 7;
  const int sb0 = ((fk ^ e7) << 4);            // kk=0 slot byte
  const int sb1 = (((4 + fk) ^ e7) << 4);      // kk=1 slot byte
  const int a_b = (wr * 128 + frow) * 128;
  const int b_b = 32768 + (wc * 64 + frow) * 128;

  f32x4 acc[8][4] = {};

  auto GLA = [&](int kt, int q, int buf) {
    gload16(aP + (size_t)(q * 64) * KDIM + (size_t)kt * 64,
            lds + buf * 65536 + q * 8192 + ldst);
  };
  auto GLB = [&](int kt, int q, int buf) {
    gload16(bP + (size_t)(q * 64) * KDIM + (size_t)kt * 64,
            lds + buf * 65536 + 32768 + q * 8192 + ldst);
  };

  auto phases = [&](int kt, bool s1, bool s2, bool s3, int f2, int f4) {
    const char* lb = lds + (kt & 1) * 65536;
    const int ob = (kt & 1) ^ 1;               // buffer of tile kt+1
    const int cb = (kt & 1);                   // buffer of tile kt+2
    bf16x8 av[4], bv0[4], bv1[4];
    // ---- phase 1: av(m0-3,kk0) + all bv; stage A1,A3(kt+1) ----
#pragma unroll
    for (int m = 0; m < 4; ++m) av[m]  = *(const bf16x8*)(lb + a_b + m * 2048 + sb0);
#pragma unroll
    for (int n = 0; n < 4; ++n) bv0[n] = *(const bf16x8*)(lb + b_b + n * 2048 + sb0);
#pragma unroll
    for (int n = 0; n < 4; ++n) bv1[n] = *(const bf16x8*)(lb + b_b + n * 2048 + sb1);
    if (s1) { GLA(kt + 1, 1, ob); GLA(kt + 1, 3, ob); }
    BAR();
    __builtin_amdgcn_s_setprio(1);
#pragma unroll
    for (int m = 0; m < 4; ++m)
#pragma unroll
      for (int n = 0; n < 4; ++n)
        acc[m][n] = __builtin_amdgcn_mfma_f32_16x16x32_bf16(av[m], bv0[n], acc[m][n], 0, 0, 0);
    __builtin_amdgcn_s_setprio(0);
    BAR();
    // ---- phase 2: av(m0-3,kk1); stage B0,B1(kt+2); fence f2 ----
#pragma unroll
    for (int m = 0; m < 4; ++m) av[m] = *(const bf16x8*)(lb + a_b + m * 2048 + sb1);
    if (s2) { GLB(kt + 2, 0, cb); GLB(kt + 2, 1, cb); }
    BAR();
    __builtin_amdgcn_s_setprio(1);
#pragma unroll
    for (int m = 0; m < 4; ++m)
#pragma unroll
      for (int n = 0; n < 4; ++n)
        acc[m][n] = __builtin_amdgcn_mfma_f32_16x16x32_bf16(av[m], bv1[n], acc[m][n], 0, 0, 0);
    __builtin_amdgcn_s_setprio(0);
    if (f2 == 0) WAITVM(10); else if (f2 == 1) WAITVM(8); else WAITVM(0);
    BAR();
    // ---- phase 3: av(m4-7,kk0); stage B2,B3,A0,A2(kt+2) ----
#pragma unroll
    for (int m = 0; m < 4; ++m) av[m] = *(const bf16x8*)(lb + a_b + (m + 4) * 2048 + sb0);
    if (s3) { GLB(kt + 2, 2, cb); GLB(kt + 2, 3, cb); GLA(kt + 2, 0, cb); GLA(kt + 2, 2, cb); }
    BAR();
    __builtin_amdgcn_s_setprio(1);
#pragma unroll
    for (int m = 0; m < 4; ++m)
#pragma unroll
      for (int n = 0; n < 4; ++n)
        acc[m + 4][n] = __builtin_amdgcn_mfma_f32_16x16x32_bf16(av[m], bv0[n], acc[m + 4][n], 0, 0, 0);
    __builtin_amdgcn_s_setprio(0);
    BAR();
    // ---- phase 4: av(m4-7,kk1); fence f4 ----
#pragma unroll
    for (int m = 0; m < 4; ++m) av[m] = *(const bf16x8*)(lb + a_b + (m + 4) * 2048 + sb1);
    BAR();
    __builtin_amdgcn_s_setprio(1);
#pragma unroll
    for (int m = 0; m < 4; ++m)
#pragma unroll
      for (int n = 0; n < 4; ++n)
        acc[m + 4][n] = __builtin_amdgcn_mfma_f32_16x16x32_bf16(av[m], bv1[n], acc[m + 4][n], 0, 0, 0);
    __builtin_amdgcn_s_setprio(0);
    if (f4 == 0) WAITVM(8); else if (f4 == 1) WAITVM(2); else WAITVM(0);
    BAR();
  };

  // prologue: FIFO = [tile0 A0,A2,B0-3 (6)] [A1,A3(0) (2)] [B0,B1(1) (2)] [B2,B3,A0,A2(1) (4)]
  GLA(0, 0, 0); GLA(0, 2, 0); GLB(0, 0, 0); GLB(0, 1, 0); GLB(0, 2, 0); GLB(0, 3, 0);
  GLA(0, 1, 0); GLA(0, 3, 0);
  GLB(1, 0, 1); GLB(1, 1, 1);
  GLB(1, 2, 1); GLB(1, 3, 1); GLA(1, 0, 1); GLA(1, 2, 1);
  WAITVM(8);                                   // tile0's first 6 landed
  BAR();

#pragma unroll 1
  for (int kt = 0; kt < NT - 2; ++kt)
    phases(kt, true, true, true, 0, 0);
  phases(NT - 2, true, false, false, 1, 1);
  phases(NT - 1, false, false, false, 2, 2);

  // epilogue: C/D layout col = lane&15, row = (lane>>4)*4 + j
#pragma unroll
  for (int m = 0; m < 8; ++m) {
#pragma unroll
    for (int j = 0; j < 4; ++j) {
      const int grow = bm0 + wr * 128 + m * 16 + (lane >> 4) * 4 + j;
      float* prow = P + (size_t)split * ((size_t)N_NODES * N_IN) + (size_t)grow * N_IN;
#pragma unroll
      for (int n = 0; n < 4; ++n) {
        const int gcol = bn0 + wc * 64 + n * 16 + (lane & 15);
        prow[gcol] = acc[m][n][j];
      }
    }
  }
}

// ---- 128x128-tile GEMM (gemm2): out = tanh(A @ B^T + bias), verified structure ----
template<int KDIM>
__global__ __launch_bounds__(256, 2) void k_gemm(
    const bf16* __restrict__ A, const bf16* __restrict__ B,
    const float* __restrict__ bias, float* __restrict__ outf) {
  constexpr int NT = KDIM / 64;
  constexpr int NBLK = 256;
  __shared__ __attribute__((aligned(128))) char lds[2 * 32768];

  const int bid = blockIdx.x;
  const int logical = (bid & 7) * (NBLK / 8) + (bid >> 3);
  const int bm0 = (logical >> 2) * 128;
  const int bn0 = (logical & 3) * 128;

  const int tid = threadIdx.x;
  const int wid = tid >> 6;
  const int lane = tid & 63;
  const int wr = wid & 1, wc = wid >> 1;

  const int srow = tid >> 3;
  const int scol = ((tid & 7) ^ (srow & 7)) << 3;
  const size_t a_src = (size_t)(bm0 + srow) * KDIM + scol;
  const size_t b_src = (size_t)(bn0 + srow) * KDIM + scol;

  const int frow = lane & 15;
  const int fk = lane >> 4;
  const int swz = (lane & 7) << 4;
  const int a_row_byte = (wr * 64 + frow) * 128;
  const int b_row_byte = 16384 + (wc * 64 + frow) * 128;

  f32x4 acc[4][4] = {};

  auto stage = [&](int t) {
    char* lbase = lds + (t & 1) * 32768;
    const bf16* ag = A + a_src + (size_t)t * 64;
    const bf16* bg = B + b_src + (size_t)t * 64;
#pragma unroll
    for (int ch = 0; ch < 4; ++ch) {
      gload16(ag + (size_t)(ch * 32) * KDIM, lbase + ch * 4096 + wid * 1024);
      gload16(bg + (size_t)(ch * 32) * KDIM, lbase + 16384 + ch * 4096 + wid * 1024);
    }
  };

  auto compute = [&](int t) {
    const char* lbase = lds + (t & 1) * 32768;
#pragma unroll
    for (int kk = 0; kk < 2; ++kk) {
      const int colb = (kk * 64 + fk * 16) ^ swz;
      bf16x8 av[4], bv[4];
#pragma unroll
      for (int m = 0; m < 4; ++m)
        av[m] = *reinterpret_cast<const bf16x8*>(lbase + a_row_byte + m * 2048 + colb);
#pragma unroll
      for (int n = 0; n < 4; ++n)
        bv[n] = *reinterpret_cast<const bf16x8*>(lbase + b_row_byte + n * 2048 + colb);
#pragma unroll
      for (int m = 0; m < 4; ++m)
#pragma unroll
        for (int n = 0; n < 4; ++n)
          acc[m][n] = __builtin_amdgcn_mfma_f32_16x16x32_bf16(av[m], bv[n], acc[m][n], 0, 0, 0);
    }
  };

  stage(0);
#pragma unroll 1
  for (int t = 0; t < NT - 1; ++t) {
    stage(t + 1);
    WAITVM(8);
    BAR();
    compute(t);
    BAR();
  }
  WAITVM(0);
  BAR();
  compute(NT - 1);

#pragma unroll
  for (int m = 0; m < 4; ++m) {
#pragma unroll
    for (int j = 0; j < 4; ++j) {
      const int grow = bm0 + wr * 64 + m * 16 + (lane >> 4) * 4 + j;
      float* orow = outf + (size_t)grow * N_OUT;
#pragma unroll
      for (int n = 0; n < 4; ++n) {
        const int gcol = bn0 + wc * 64 + n * 16 + (lane & 15);
        float v = acc[m][n][j] + bias[gcol];
        v = fminf(fmaxf(v, -15.f), 15.f);
        const float e = __expf(2.f * v);
        orow[gcol] = (e - 1.f) / (e + 1.f);
      }
    }
  }
}

// ---- split-K reduce: Hm = bf16(d_i * (P0+P1+P2+P3))  (+I already inside adjb) ----
__global__ __launch_bounds__(256) void k_red(const float* __restrict__ P,
                                             const float* __restrict__ dv,
                                             bf16* __restrict__ Hm) {
  const int t = blockIdx.x * 256 + threadIdx.x;
  const int row = t >> 7;
  const int col = (t & 127) << 2;
  const size_t off = (size_t)row * N_IN + col;
  constexpr size_t S = (size_t)N_NODES * N_IN;
  const float d = dv[row];
  const float4 p0 = *reinterpret_cast<const float4*>(P + off);
  const float4 p1 = *reinterpret_cast<const float4*>(P + S + off);
  const float4 p2 = *reinterpret_cast<const float4*>(P + 2 * S + off);
  const float4 p3 = *reinterpret_cast<const float4*>(P + 3 * S + off);
  bf16x4 o = { (bf16)(d * ((p0.x + p1.x) + (p2.x + p3.x))),
               (bf16)(d * ((p0.y + p1.y) + (p2.y + p3.y))),
               (bf16)(d * ((p0.z + p1.z) + (p2.z + p3.z))),
               (bf16)(d * ((p0.w + p1.w) + (p2.w + p3.w))) };
  *reinterpret_cast<bf16x4*>(Hm + off) = o;
}

extern "C" void kernel_launch(void* const* d_in, const int* in_sizes, int n_in,
                              void* d_out, int out_size, void* d_ws, size_t ws_size,
                              hipStream_t stream) {
  const float* H   = (const float*)d_in[0];
  const float* adj = (const float*)d_in[1];
  const float* W   = (const float*)d_in[2];
  const float* b   = (const float*)d_in[3];
  float* out = (float*)d_out;
  char* ws = (char*)d_ws;

  bf16*  adjb = (bf16*)(ws);                    // 8192*8192*2 = 134217728
  bf16*  Hst  = (bf16*)(ws + 134217728);        // 512*8192*2  = 8388608
  bf16*  Hm   = (bf16*)(ws + 142606336);        // 8192*512*2  = 8388608
  bf16*  Wb   = (bf16*)(ws + 150994944);        // 512*512*2   = 524288
  float* part = (float*)(ws + 151519232);       // 128*8192*4  = 4194304
  float* dv   = (float*)(ws + 155713536);       // 8192*4      = 32768
  float* P    = (float*)(ws + 155746304);       // 4*8192*512*4 = 67108864

  k_colsum_cvt<<<dim3(8, 128), 256, 0, stream>>>(adj, adjb, part);
  k_dvec<<<32, 256, 0, stream>>>(part, dv);
  k_hst<<<dim3(128, 8), 256, 0, stream>>>(H, dv, Hst);
  k_wcvt<<<256, 256, 0, stream>>>(W, Wb);
  // P[s] = (adj+I)b[:, s-quarter] @ Hst[s-quarter]^T   (split-K=4, f32 partials)
  k_gemm256<8192, 4><<<256, 512, 0, stream>>>(adjb, Hst, P);
  // Hm = d_i*(P0+P1+P2+P3)   (bf16)
  k_red<<<4096, 256, 0, stream>>>(P, dv, Hm);
  // out = tanh(Hm @ W^T + b)  (f32)
  k_gemm<512><<<256, 256, 0, stream>>>(Hm, Wb, b, out);
}